// Round 4
// baseline (3389.936 us; speedup 1.0000x reference)
//
#include <hip/hip_runtime.h>
#include <hip/hip_cooperative_groups.h>

namespace cg = cooperative_groups;

// APPNP: out = log_softmax(z_K), z_{k+1} = 0.9*A z_k + 0.1*h, z0 = h
// h = relu(x@W1+b1)@W2 + b2
// DTYPE-ADAPTIVE: float arrays may be fp32 or bf16; detected on-device from x's
// bit patterns (flag in ws). z/h always bf16; edge records packed int2
// {col, fp32-bits(val)} (one 8B random store in scatter instead of 4B+2B to
// two arrays -> halves dirtied lines; one 8B broadcast load in prop).
// Propagation: ONE cooperative persistent kernel, 10 steps with grid.sync();
// each block stages its CSR slice into LDS once (reused across all steps).
// Fallback to 10 separate dispatches if cooperative launch unavailable.

typedef unsigned short ushort_t;
typedef short short8 __attribute__((ext_vector_type(8)));
typedef float f32x4 __attribute__((ext_vector_type(4)));

#define NFEAT 512
#define NHID 256
#define NCLASS 40

static __device__ __forceinline__ float b2f(ushort_t u) {
    unsigned v = ((unsigned)u) << 16;
    float f;
    __builtin_memcpy(&f, &v, 4);
    return f;
}
static __device__ __forceinline__ ushort_t f2b(float f) {
    unsigned u;
    __builtin_memcpy(&u, &f, 4);
    unsigned r = u + 0x7FFFu + ((u >> 16) & 1u);
    return (ushort_t)(r >> 16);
}
static __device__ __forceinline__ ushort_t san_u(ushort_t u) {
    return ((u & 0x7F80u) == 0x7F80u) ? (ushort_t)0 : u;
}
static __device__ __forceinline__ float ldmix(const void* p, size_t i, int isbf) {
    if (isbf) return b2f(san_u(((const ushort_t*)p)[i]));
    return ((const float*)p)[i];
}
static __device__ __forceinline__ void stz(void* p, size_t i, int zbf, float v) {
    if (zbf) ((ushort_t*)p)[i] = f2b(v);
    else ((float*)p)[i] = v;
}

// async global->LDS, 16B per lane. LDS dest is wave-uniform base + lane*16.
static __device__ __forceinline__ void gld_lds16(const ushort_t* g, ushort_t* l) {
    __builtin_amdgcn_global_load_lds(
        (const __attribute__((address_space(1))) unsigned int*)g,
        (__attribute__((address_space(3))) unsigned int*)l, 16, 0, 0);
}

// ---------------- dtype detect ----------------
__global__ void detect_kernel(const ushort_t* __restrict__ x, int* __restrict__ flag) {
    __shared__ int cnt_s;
    if (threadIdx.x == 0) cnt_s = 0;
    __syncthreads();
    int c = 0;
    for (int i = threadIdx.x; i < 2048; i += 256) {
        ushort_t u = x[2 * i];
        int e = (u >> 7) & 0xFF;
        if (e >= 107 && e <= 141) c++;
    }
    atomicAdd(&cnt_s, c);
    __syncthreads();
    if (threadIdx.x == 0) flag[0] = (cnt_s >= 1024) ? 1 : 0;
}

// ---------------- CSR build ----------------

__global__ void zero_kernel(int* __restrict__ p, int n) {
    int i = blockIdx.x * 256 + threadIdx.x;
    if (i < n) p[i] = 0;
}

__global__ void hist_kernel(const int* __restrict__ row, int* __restrict__ deg, int e, int n) {
    int i = blockIdx.x * 256 + threadIdx.x;
    if (i < e) {
        int r = row[i];
        if ((unsigned)r < (unsigned)n) atomicAdd(&deg[r], 1);
    }
}

__global__ void scan_blocksum(const int* __restrict__ deg, int* __restrict__ bsum, int n) {
    __shared__ int s[256];
    int t = threadIdx.x;
    int i = blockIdx.x * 256 + t;
    s[t] = (i < n) ? deg[i] : 0;
    __syncthreads();
    for (int o = 128; o; o >>= 1) {
        if (t < o) s[t] += s[t + o];
        __syncthreads();
    }
    if (t == 0) bsum[blockIdx.x] = s[0];
}

__global__ void scan_bsum_excl(int* __restrict__ bsum, int nb) {
    __shared__ int s[512];
    int t = threadIdx.x;
    int v = (t < nb) ? bsum[t] : 0;
    int own = v;
    s[t] = v;
    __syncthreads();
    for (int o = 1; o < 512; o <<= 1) {
        int add = (t >= o) ? s[t - o] : 0;
        __syncthreads();
        s[t] += add;
        __syncthreads();
    }
    if (t < nb) bsum[t] = s[t] - own;
}

__global__ void scan_emit(const int* __restrict__ deg, const int* __restrict__ bsum,
                          int* __restrict__ row_start, int* __restrict__ cursor, int n) {
    __shared__ int s[256];
    int t = threadIdx.x;
    int i = blockIdx.x * 256 + t;
    int v = (i < n) ? deg[i] : 0;
    int own = v;
    s[t] = v;
    __syncthreads();
    for (int o = 1; o < 256; o <<= 1) {
        int add = (t >= o) ? s[t - o] : 0;
        __syncthreads();
        s[t] += add;
        __syncthreads();
    }
    if (i < n) {
        int rs = bsum[blockIdx.x] + s[t] - own;
        row_start[i] = rs;
        cursor[i] = rs;
    }
}

__global__ void scatter_kernel(const int* __restrict__ row, const int* __restrict__ col,
                               const void* __restrict__ vals, int* __restrict__ cursor,
                               int2* __restrict__ cs, const int* __restrict__ flag, int e,
                               int n) {
    int i = blockIdx.x * 256 + threadIdx.x;
    if (i < e) {
        int isbf = flag[0];
        int r = row[i];
        if ((unsigned)r >= (unsigned)n) return;
        int p = atomicAdd(&cursor[r], 1);
        if ((unsigned)p < (unsigned)e) {
            int c = col[i];
            float v = ldmix(vals, i, isbf);
            int2 rec;
            rec.x = ((unsigned)c < (unsigned)n) ? c : 0;
            __builtin_memcpy(&rec.y, &v, 4);
            cs[p] = rec;
        }
    }
}

// ---------------- weight fragment pre-layout (canonical bf16) ----------------
// B-frag (mfma_f32_16x16x32_bf16): lane l holds B[k=(l>>4)*8+j][n=l&15], j=0..7.
// w1f layout: [kb 0..15][nt 0..15][lane 0..63][8] -> per-kb slice is 16KB linear.

__global__ void w1frag_kernel(const void* __restrict__ W1, ushort_t* __restrict__ w1f,
                              const int* __restrict__ flag) {
    int t = blockIdx.x * 256 + threadIdx.x;  // 16384 total
    if (t >= 16 * 16 * 64) return;
    int isbf = flag[0];
    int l = t & 63, nt = (t >> 6) & 15, kb = t >> 10;
    ushort_t tmp[8];
#pragma unroll
    for (int j = 0; j < 8; j++) {
        int k = kb * 32 + (l >> 4) * 8 + j;
        int nn = nt * 16 + (l & 15);
        tmp[j] = f2b(ldmix(W1, (size_t)k * NHID + nn, isbf));
    }
    *(short8*)(w1f + (size_t)t * 8) = *(short8*)tmp;
}

__global__ void w2frag_kernel(const void* __restrict__ W2, ushort_t* __restrict__ w2f,
                              const int* __restrict__ flag) {
    int t = blockIdx.x * 256 + threadIdx.x;  // 1536 total
    if (t >= 8 * 3 * 64) return;
    int isbf = flag[0];
    int l = t % 64;
    int nt = (t / 64) % 3;
    int kb = t / 192;
    ushort_t tmp[8];
#pragma unroll
    for (int j = 0; j < 8; j++) {
        int k = kb * 32 + (l >> 4) * 8 + j;
        int nn = nt * 16 + (l & 15);
        tmp[j] = (nn < NCLASS) ? f2b(ldmix(W2, (size_t)k * NCLASS + nn, isbf)) : (ushort_t)0;
    }
    *(short8*)(w2f + (size_t)t * 8) = *(short8*)tmp;
}

// ---------------- fused MLP ----------------

template <int ISBF>
static __device__ __forceinline__ short8 load_afrag(const void* __restrict__ x, size_t base) {
    short8 av;
    if (ISBF) {
        av = *(const short8*)((const ushort_t*)x + base);
#pragma unroll
        for (int j = 0; j < 8; j++) {
            ushort_t u = (ushort_t)av[j];
            if ((u & 0x7F80u) == 0x7F80u) av[j] = 0;
        }
    } else {
        const float* xf = (const float*)x + base;
        f32x4 a0 = *(const f32x4*)xf;
        f32x4 a1 = *(const f32x4*)(xf + 4);
#pragma unroll
        for (int j = 0; j < 4; j++) {
            av[j] = (short)f2b(a0[j]);
            av[4 + j] = (short)f2b(a1[j]);
        }
    }
    return av;
}

#define APITCH 42

template <int ISBF>
static __device__ __forceinline__ void gemm1_staged(const void* __restrict__ x,
                                                    const ushort_t* __restrict__ w1f,
                                                    size_t xbase, ushort_t* Bl0, ushort_t* Bl1,
                                                    ushort_t* awr0, ushort_t* awr1,
                                                    const ushort_t* ard0, const ushort_t* ard1,
                                                    const ushort_t* brd0, const ushort_t* brd1,
                                                    f32x4 (&acc)[16], int wv, int l) {
    {
        short8 a0 = load_afrag<ISBF>(x, xbase);
        *(short8*)awr0 = a0;
        const ushort_t* src = w1f + (size_t)wv * 512 + (size_t)l * 8;
#pragma unroll
        for (int i = 0; i < 4; i++) gld_lds16(src + i * 2048, Bl0 + wv * 512 + i * 2048);
    }
    __syncthreads();

#pragma unroll
    for (int kb = 0; kb < 16; kb++) {
        const bool even = (kb & 1) == 0;
        const ushort_t* brd = even ? brd0 : brd1;
        const ushort_t* ard = even ? ard0 : ard1;
        ushort_t* awrn = even ? awr1 : awr0;
        ushort_t* bln = even ? Bl1 : Bl0;
        short8 an;
        if (kb < 15) {
            an = load_afrag<ISBF>(x, xbase + (size_t)(kb + 1) * 32);
            const ushort_t* src =
                w1f + (size_t)(kb + 1) * 8192 + (size_t)wv * 512 + (size_t)l * 8;
#pragma unroll
            for (int i = 0; i < 4; i++) gld_lds16(src + i * 2048, bln + wv * 512 + i * 2048);
        }
        short8 af = *(const short8*)ard;
#pragma unroll
        for (int nt = 0; nt < 16; nt++) {
            short8 bf = *(const short8*)(brd + nt * 512);
            acc[nt] = __builtin_amdgcn_mfma_f32_16x16x32_bf16(af, bf, acc[nt], 0, 0, 0);
        }
        if (kb < 15) *(short8*)awrn = an;
        __syncthreads();
    }
}

__global__ __launch_bounds__(256, 3) void mlp_kernel(const void* __restrict__ x,
                                                     const ushort_t* __restrict__ w1f,
                                                     const ushort_t* __restrict__ w2f,
                                                     const void* __restrict__ b1,
                                                     const void* __restrict__ b2,
                                                     void* __restrict__ h,
                                                     const int* __restrict__ flag, int zbf,
                                                     int n) {
    __shared__ __align__(16) ushort_t pool[21760];
    ushort_t* Bl0 = pool;
    ushort_t* Bl1 = pool + 8192;
    ushort_t* Al0 = pool + 16384;
    ushort_t* Al1 = pool + 16384 + 2688;
    ushort_t* Hl = pool;  // pitch 264

    const int t = threadIdx.x;
    const int isbf = flag[0];
    const int wv = t >> 6, l = t & 63;
    const int lq = l >> 4, lr = l & 15;
    const int m0 = blockIdx.x * 64;

    const int rS = t >> 2, qS = t & 3;
    int rowS = m0 + rS;
    if (rowS > n - 1) rowS = n - 1;
    const size_t xbase = (size_t)rowS * NFEAT + (size_t)qS * 8;
    ushort_t* awr0 = Al0 + rS * APITCH + qS * 8;
    ushort_t* awr1 = Al1 + rS * APITCH + qS * 8;
    const ushort_t* ard0 = Al0 + (wv * 16 + lr) * APITCH + lq * 8;
    const ushort_t* ard1 = Al1 + (wv * 16 + lr) * APITCH + lq * 8;
    const ushort_t* brd0 = Bl0 + l * 8;
    const ushort_t* brd1 = Bl1 + l * 8;

    f32x4 acc[16];
#pragma unroll
    for (int i = 0; i < 16; i++) acc[i] = (f32x4){0.f, 0.f, 0.f, 0.f};

    if (isbf)
        gemm1_staged<1>(x, w1f, xbase, Bl0, Bl1, awr0, awr1, ard0, ard1, brd0, brd1, acc, wv, l);
    else
        gemm1_staged<0>(x, w1f, xbase, Bl0, Bl1, awr0, awr1, ard0, ard1, brd0, brd1, acc, wv, l);

    float bias1 = ldmix(b1, 0, isbf);
#pragma unroll
    for (int nt = 0; nt < 16; nt++) {
#pragma unroll
        for (int i = 0; i < 4; i++) {
            float v = acc[nt][i] + bias1;
            v = fmaxf(v, 0.f);
            Hl[(wv * 16 + lq * 4 + i) * 264 + nt * 16 + lr] = f2b(v);
        }
    }
    __syncthreads();

    f32x4 acc2[3];
#pragma unroll
    for (int i = 0; i < 3; i++) acc2[i] = (f32x4){0.f, 0.f, 0.f, 0.f};
    const ushort_t* hp = Hl + (wv * 16 + lr) * 264 + lq * 8;
#pragma unroll
    for (int kb = 0; kb < 8; kb++) {
        short8 afrag = *(const short8*)(hp + kb * 32);
#pragma unroll
        for (int nt = 0; nt < 3; nt++) {
            short8 bfrag = *(const short8*)(w2f + ((size_t)(kb * 3 + nt) * 64 + l) * 8);
            acc2[nt] = __builtin_amdgcn_mfma_f32_16x16x32_bf16(afrag, bfrag, acc2[nt], 0, 0, 0);
        }
    }

    float bias2 = ldmix(b2, 0, isbf);
#pragma unroll
    for (int nt = 0; nt < 3; nt++) {
#pragma unroll
        for (int i = 0; i < 4; i++) {
            int rowg = m0 + wv * 16 + lq * 4 + i;
            int colg = nt * 16 + lr;
            if (rowg < n && colg < NCLASS)
                stz(h, (size_t)rowg * NCLASS + colg, zbf, acc2[nt][i] + bias2);
        }
    }
}

// ------------- fused propagation: 10 steps, one cooperative dispatch ---------
// grid = 4 blocks/CU (LDS: 36.9KB/block -> exactly 4 resident; launch_bounds
// caps VGPR for 16 waves/CU). Each block owns a contiguous node chunk and
// stages its CSR slice (packed int2 records) into LDS ONCE; all 10 steps
// re-read edges from LDS (uniform-address broadcast, conflict-free) instead
// of global + shfl. z ping-pongs zA/zB in global (neighbors' rows are read
// by other blocks, so z must stay global; grid.sync() per step).

#define CSCAP 4096
#define NMAX 512

__global__ __launch_bounds__(256, 4) void prop_fused(void* __restrict__ zA,
                                                     void* __restrict__ zB,
                                                     const void* __restrict__ h,
                                                     const int* __restrict__ row_start,
                                                     const int* __restrict__ deg,
                                                     const int2* __restrict__ cs, int n,
                                                     int etot) {
    __shared__ int2 lrec[CSCAP];
    __shared__ int lstart[NMAX];
    __shared__ int ldeg[NMAX];

    const int t = threadIdx.x;
    const int wv = t >> 6, lane = t & 63;
    const int grid = gridDim.x;
    const int chunk = (n + grid - 1) / grid;
    const int node0 = blockIdx.x * chunk;
    int nodes = n - node0;
    if (nodes > chunk) nodes = chunk;
    if (nodes < 0) nodes = 0;

    int base = 0, total = 0;
    if (nodes > 0) {
        base = row_start[node0];
        int endi = node0 + nodes;
        total = ((endi < n) ? row_start[endi] : etot) - base;
    }
    const bool meta_ok = (nodes <= NMAX);
    if (meta_ok) {
        for (int k = t; k < nodes; k += 256) {
            lstart[k] = row_start[node0 + k] - base;
            ldeg[k] = deg[node0 + k];
        }
    }
    const int cap = (total < CSCAP) ? total : CSCAP;
    for (int i = t; i < cap; i += 256) lrec[i] = cs[base + i];
    __syncthreads();

    cg::grid_group gg = cg::this_grid();
    const bool laneok = lane < NCLASS;

    for (int step = 0; step < 10; step++) {
        const ushort_t* zi =
            (const ushort_t*)((step == 0) ? h : ((step & 1) ? zA : zB));
        ushort_t* zo = (ushort_t*)((step & 1) ? zB : zA);

        for (int idx = wv; idx < nodes; idx += 4) {
            int st, d;
            if (meta_ok) {
                st = lstart[idx];
                d = ldeg[idx];
            } else {
                st = row_start[node0 + idx] - base;
                d = deg[node0 + idx];
            }
            float acc = 0.f;
            if (st + d <= cap) {
                for (int e = 0; e < d; e += 8) {
                    int cc[8];
                    float vv[8];
#pragma unroll
                    for (int k = 0; k < 8; k++) {
                        int ee = e + k;
                        int ii = st + ((ee < d) ? ee : d - 1);
                        int2 r = lrec[ii];
                        cc[k] = r.x;
                        float fv;
                        __builtin_memcpy(&fv, &r.y, 4);
                        vv[k] = (ee < d) ? fv : 0.f;
                    }
                    if (laneok) {
                        float zv[8];
#pragma unroll
                        for (int k = 0; k < 8; k++)
                            zv[k] = b2f(zi[(size_t)cc[k] * NCLASS + lane]);
#pragma unroll
                        for (int k = 0; k < 8; k++) acc += vv[k] * zv[k];
                    }
                }
            } else {
                for (int e = 0; e < d; e += 8) {
                    int cc[8];
                    float vv[8];
#pragma unroll
                    for (int k = 0; k < 8; k++) {
                        int ee = e + k;
                        int ii = base + st + ((ee < d) ? ee : d - 1);
                        int2 r = cs[ii];
                        cc[k] = r.x;
                        float fv;
                        __builtin_memcpy(&fv, &r.y, 4);
                        vv[k] = (ee < d) ? fv : 0.f;
                    }
                    if (laneok) {
                        float zv[8];
#pragma unroll
                        for (int k = 0; k < 8; k++)
                            zv[k] = b2f(zi[(size_t)cc[k] * NCLASS + lane]);
#pragma unroll
                        for (int k = 0; k < 8; k++) acc += vv[k] * zv[k];
                    }
                }
            }
            if (laneok) {
                int w = node0 + idx;
                float hv = b2f(((const ushort_t*)h)[(size_t)w * NCLASS + lane]);
                float r = 0.9f * acc + 0.1f * hv;
                zo[(size_t)w * NCLASS + lane] = f2b(r);
            }
        }
        __threadfence();
        gg.sync();
    }
}

// ---------------- fallback propagation (one step per dispatch) --------------

__global__ __launch_bounds__(256) void prop_kernel(const void* __restrict__ zin,
                                                   void* __restrict__ zout,
                                                   const void* __restrict__ h,
                                                   const int* __restrict__ row_start,
                                                   const int* __restrict__ deg,
                                                   const int2* __restrict__ cs, int n) {
    int w = blockIdx.x * 4 + (threadIdx.x >> 6);
    int lane = threadIdx.x & 63;
    if (w >= n) return;
    int start = row_start[w];
    int d = deg[w];
    const bool laneok = lane < NCLASS;
    float acc = 0.f;
    for (int base = 0; base < d; base += 64) {
        int m = d - base;
        if (m > 64) m = 64;
        int c = 0;
        float v = 0.f;
        if (lane < m) {
            int2 r = cs[(size_t)start + base + lane];
            c = r.x;
            __builtin_memcpy(&v, &r.y, 4);
        }
        for (int j = 0; j < m; j += 8) {
            int cc[8];
            float vv[8];
#pragma unroll
            for (int k = 0; k < 8; k++) {
                cc[k] = __shfl(c, j + k);
                vv[k] = __shfl(v, j + k);
            }
            if (laneok) {
                float zv[8];
#pragma unroll
                for (int k = 0; k < 8; k++)
                    zv[k] = b2f(((const ushort_t*)zin)[(size_t)cc[k] * NCLASS + lane]);
#pragma unroll
                for (int k = 0; k < 8; k++) acc += vv[k] * zv[k];
            }
        }
    }
    if (laneok) {
        float hv = b2f(((const ushort_t*)h)[(size_t)w * NCLASS + lane]);
        float r = 0.9f * acc + 0.1f * hv;
        ((ushort_t*)zout)[(size_t)w * NCLASS + lane] = f2b(r);
    }
}

// ---------------- log_softmax; out dtype follows detected input dtype ---------

__global__ __launch_bounds__(256) void lsm_kernel(const void* __restrict__ z,
                                                  void* __restrict__ out,
                                                  const int* __restrict__ flag, int n) {
    int w = blockIdx.x * 4 + (threadIdx.x >> 6);
    int lane = threadIdx.x & 63;
    if (w >= n) return;
    int isbf = flag[0];
    float v = (lane < NCLASS) ? b2f(((const ushort_t*)z)[(size_t)w * NCLASS + lane]) : -INFINITY;
    float m = v;
    for (int o = 32; o; o >>= 1) m = fmaxf(m, __shfl_xor(m, o));
    float e = (lane < NCLASS) ? __expf(v - m) : 0.f;
    float s = e;
    for (int o = 32; o; o >>= 1) s += __shfl_xor(s, o);
    if (lane < NCLASS) {
        float r = v - m - __logf(s);
        if (isbf) ((ushort_t*)out)[(size_t)w * NCLASS + lane] = f2b(r);
        else ((float*)out)[(size_t)w * NCLASS + lane] = r;
    }
}

// ---------------- launch ----------------

extern "C" void kernel_launch(void* const* d_in, const int* in_sizes, int n_in, void* d_out,
                              int out_size, void* d_ws, size_t ws_size, hipStream_t stream) {
    const void* x = d_in[0];
    const int* row = (const int*)d_in[1];
    const int* col = (const int*)d_in[2];
    const void* vals = d_in[3];
    const void* W1 = d_in[4];
    const void* b1 = d_in[5];
    const void* W2 = d_in[6];
    const void* b2 = d_in[7];

    const int N = in_sizes[0] / NFEAT;  // 100000
    const int E = in_sizes[1];          // 1600000

    const size_t ez = 2;  // z/h always bf16

    char* ws = (char*)d_ws;
    size_t off = 0;
    auto take = [&](size_t bytes) {
        size_t o = off;
        off = (off + bytes + 255) & ~(size_t)255;
        return (void*)(ws + o);
    };
    void* h = take((size_t)N * NCLASS * ez);
    void* zA = take((size_t)N * NCLASS * ez);
    void* zB = take((size_t)N * NCLASS * ez);
    int2* cs = (int2*)take((size_t)E * 8);
    int* deg = (int*)take((size_t)N * 4);
    int* row_start = (int*)take((size_t)N * 4);
    int* cursor = (int*)take((size_t)N * 4);
    ushort_t* w1f = (ushort_t*)take((size_t)NFEAT * NHID * 2);
    ushort_t* w2f = (ushort_t*)take((size_t)8 * 3 * 64 * 8 * 2);
    int* bsum = (int*)take(512 * 4);
    int* flag = (int*)take(256);

    const int NB = (N + 255) / 256;  // 391 <= 512
    const int EB = (E + 255) / 256;
    const int GB = (N + 63) / 64;
    const int PB = (N + 3) / 4;

    detect_kernel<<<1, 256, 0, stream>>>((const ushort_t*)x, flag);

    // CSR build
    zero_kernel<<<(N + 255) / 256, 256, 0, stream>>>(deg, N);
    hist_kernel<<<EB, 256, 0, stream>>>(row, deg, E, N);
    scan_blocksum<<<NB, 256, 0, stream>>>(deg, bsum, N);
    scan_bsum_excl<<<1, 512, 0, stream>>>(bsum, NB);
    scan_emit<<<NB, 256, 0, stream>>>(deg, bsum, row_start, cursor, N);
    scatter_kernel<<<EB, 256, 0, stream>>>(row, col, vals, cursor, cs, flag, E, N);

    // weight fragments
    w1frag_kernel<<<64, 256, 0, stream>>>(W1, w1f, flag);
    w2frag_kernel<<<6, 256, 0, stream>>>(W2, w2f, flag);

    // fused MLP -> h
    mlp_kernel<<<GB, 256, 0, stream>>>(x, w1f, w2f, b1, b2, h, flag, 1, N);

    // propagation: cooperative fused (10 steps), fallback to 10 dispatches
    static int coop_state = 0;  // 0 unknown, 1 ok, -1 failed
    int launched_coop = 0;
    if (coop_state >= 0) {
        static int cached_grid = 0;
        if (cached_grid == 0) {
            int cu = 256;
            hipDeviceProp_t prop;
            if (hipGetDeviceProperties(&prop, 0) == hipSuccess && prop.multiProcessorCount > 0)
                cu = prop.multiProcessorCount;
            int occ = 0;
            if (hipOccupancyMaxActiveBlocksPerMultiprocessor(&occ, prop_fused, 256, 0) !=
                    hipSuccess ||
                occ <= 0)
                occ = 4;
            if (occ > 4) occ = 4;
            int g = cu * occ;
            if (g > 1024) g = 1024;
            if (g < 64) g = 64;
            cached_grid = g;
        }
        int n_ = N, e_ = E;
        void* ka[8];
        ka[0] = (void*)&zA;
        ka[1] = (void*)&zB;
        ka[2] = (void*)&h;
        ka[3] = (void*)&row_start;
        ka[4] = (void*)&deg;
        ka[5] = (void*)&cs;
        ka[6] = (void*)&n_;
        ka[7] = (void*)&e_;
        hipError_t err = hipLaunchCooperativeKernel(prop_fused, dim3(cached_grid), dim3(256), ka,
                                                    0, stream);
        if (err == hipSuccess) {
            coop_state = 1;
            launched_coop = 1;
            lsm_kernel<<<PB, 256, 0, stream>>>(zB, d_out, flag, N);
        } else {
            coop_state = -1;
        }
    }
    if (!launched_coop) {
        prop_kernel<<<PB, 256, 0, stream>>>(h, zA, h, row_start, deg, cs, N);
        const void* zi = zA;
        void* zo = zB;
        for (int s = 1; s < 10; s++) {
            prop_kernel<<<PB, 256, 0, stream>>>(zi, zo, h, row_start, deg, cs, N);
            const void* tmp = zi;
            zi = zo;
            zo = (void*)tmp;
        }
        lsm_kernel<<<PB, 256, 0, stream>>>(zi, d_out, flag, N);
    }
}

// Round 5
// 1004.433 us; speedup vs baseline: 3.3750x; 3.3750x over previous
//
#include <hip/hip_runtime.h>

// APPNP: out = log_softmax(z_K), z_{k+1} = 0.9*A z_k + 0.1*h, z0 = h
// h = relu(x@W1+b1)@W2 + b2
// DTYPE-ADAPTIVE: float arrays may be fp32 or bf16; detected on-device from x's
// bit patterns (flag in ws). z/h always bf16. Edge records packed int2
// {col, fp32-bits(val)}.
// prop: one dispatch per step (max occupancy), TWO nodes per wave with
// interleaved 8-deep gather batches -> 16 independent gathers in flight per
// wave (prop is MLP-bound: fused-kernel experiment r4 showed halving per-CU
// outstanding gathers quadrupled step time at identical traffic).
// scatter: XCD-sharded (block b&7 = shard, b>>3 = edge chunk) so each XCD's
// random 8B stores span 1.6MB < 4MB L2 -> lines merge before eviction
// (was 160MB writeback for 13MB payload).

typedef unsigned short ushort_t;
typedef short short8 __attribute__((ext_vector_type(8)));
typedef float f32x4 __attribute__((ext_vector_type(4)));

#define NFEAT 512
#define NHID 256
#define NCLASS 40

static __device__ __forceinline__ float b2f(ushort_t u) {
    unsigned v = ((unsigned)u) << 16;
    float f;
    __builtin_memcpy(&f, &v, 4);
    return f;
}
static __device__ __forceinline__ ushort_t f2b(float f) {
    unsigned u;
    __builtin_memcpy(&u, &f, 4);
    unsigned r = u + 0x7FFFu + ((u >> 16) & 1u);
    return (ushort_t)(r >> 16);
}
static __device__ __forceinline__ ushort_t san_u(ushort_t u) {
    return ((u & 0x7F80u) == 0x7F80u) ? (ushort_t)0 : u;
}
static __device__ __forceinline__ float ldmix(const void* p, size_t i, int isbf) {
    if (isbf) return b2f(san_u(((const ushort_t*)p)[i]));
    return ((const float*)p)[i];
}
static __device__ __forceinline__ void stz(void* p, size_t i, int zbf, float v) {
    if (zbf) ((ushort_t*)p)[i] = f2b(v);
    else ((float*)p)[i] = v;
}

// async global->LDS, 16B per lane. LDS dest is wave-uniform base + lane*16.
static __device__ __forceinline__ void gld_lds16(const ushort_t* g, ushort_t* l) {
    __builtin_amdgcn_global_load_lds(
        (const __attribute__((address_space(1))) unsigned int*)g,
        (__attribute__((address_space(3))) unsigned int*)l, 16, 0, 0);
}

// ---------------- dtype detect ----------------
__global__ void detect_kernel(const ushort_t* __restrict__ x, int* __restrict__ flag) {
    __shared__ int cnt_s;
    if (threadIdx.x == 0) cnt_s = 0;
    __syncthreads();
    int c = 0;
    for (int i = threadIdx.x; i < 2048; i += 256) {
        ushort_t u = x[2 * i];
        int e = (u >> 7) & 0xFF;
        if (e >= 107 && e <= 141) c++;
    }
    atomicAdd(&cnt_s, c);
    __syncthreads();
    if (threadIdx.x == 0) flag[0] = (cnt_s >= 1024) ? 1 : 0;
}

// ---------------- CSR build ----------------

__global__ void zero_kernel(int* __restrict__ p, int n) {
    int i = blockIdx.x * 256 + threadIdx.x;
    if (i < n) p[i] = 0;
}

__global__ void hist_kernel(const int* __restrict__ row, int* __restrict__ deg, int e, int n) {
    int i = blockIdx.x * 256 + threadIdx.x;
    if (i < e) {
        int r = row[i];
        if ((unsigned)r < (unsigned)n) atomicAdd(&deg[r], 1);
    }
}

__global__ void scan_blocksum(const int* __restrict__ deg, int* __restrict__ bsum, int n) {
    __shared__ int s[256];
    int t = threadIdx.x;
    int i = blockIdx.x * 256 + t;
    s[t] = (i < n) ? deg[i] : 0;
    __syncthreads();
    for (int o = 128; o; o >>= 1) {
        if (t < o) s[t] += s[t + o];
        __syncthreads();
    }
    if (t == 0) bsum[blockIdx.x] = s[0];
}

__global__ void scan_bsum_excl(int* __restrict__ bsum, int nb) {
    __shared__ int s[512];
    int t = threadIdx.x;
    int v = (t < nb) ? bsum[t] : 0;
    int own = v;
    s[t] = v;
    __syncthreads();
    for (int o = 1; o < 512; o <<= 1) {
        int add = (t >= o) ? s[t - o] : 0;
        __syncthreads();
        s[t] += add;
        __syncthreads();
    }
    if (t < nb) bsum[t] = s[t] - own;
}

__global__ void scan_emit(const int* __restrict__ deg, const int* __restrict__ bsum,
                          int* __restrict__ row_start, int* __restrict__ cursor, int n) {
    __shared__ int s[256];
    int t = threadIdx.x;
    int i = blockIdx.x * 256 + t;
    int v = (i < n) ? deg[i] : 0;
    int own = v;
    s[t] = v;
    __syncthreads();
    for (int o = 1; o < 256; o <<= 1) {
        int add = (t >= o) ? s[t - o] : 0;
        __syncthreads();
        s[t] += add;
        __syncthreads();
    }
    if (i < n) {
        int rs = bsum[blockIdx.x] + s[t] - own;
        row_start[i] = rs;
        cursor[i] = rs;
    }
}

// XCD-sharded scatter: shard = blockIdx&7 (round-robin XCD dispatch), chunk =
// blockIdx>>3. Each block stores only rows in its shard's node range, so one
// XCD's random stores cover a 1.6MB cs region (< 4MB L2) and merge in L2.
__global__ void scatter_kernel(const int* __restrict__ row, const int* __restrict__ col,
                               const void* __restrict__ vals, int* __restrict__ cursor,
                               int2* __restrict__ cs, const int* __restrict__ flag, int e,
                               int n, int nshard) {
    int shard = blockIdx.x & 7;
    int i = (blockIdx.x >> 3) * 256 + threadIdx.x;
    if (i >= e) return;
    int r = row[i];
    if ((unsigned)r >= (unsigned)n) return;
    int s0 = shard * nshard;
    if (r < s0 || r >= s0 + nshard) return;
    int isbf = flag[0];
    int p = atomicAdd(&cursor[r], 1);
    if ((unsigned)p < (unsigned)e) {
        int c = col[i];
        float v = ldmix(vals, i, isbf);
        int2 rec;
        rec.x = ((unsigned)c < (unsigned)n) ? c : 0;
        __builtin_memcpy(&rec.y, &v, 4);
        cs[p] = rec;
    }
}

// ---------------- weight fragment pre-layout (canonical bf16) ----------------
// B-frag (mfma_f32_16x16x32_bf16): lane l holds B[k=(l>>4)*8+j][n=l&15], j=0..7.
// w1f layout: [kb 0..15][nt 0..15][lane 0..63][8] -> per-kb slice is 16KB linear.

__global__ void w1frag_kernel(const void* __restrict__ W1, ushort_t* __restrict__ w1f,
                              const int* __restrict__ flag) {
    int t = blockIdx.x * 256 + threadIdx.x;  // 16384 total
    if (t >= 16 * 16 * 64) return;
    int isbf = flag[0];
    int l = t & 63, nt = (t >> 6) & 15, kb = t >> 10;
    ushort_t tmp[8];
#pragma unroll
    for (int j = 0; j < 8; j++) {
        int k = kb * 32 + (l >> 4) * 8 + j;
        int nn = nt * 16 + (l & 15);
        tmp[j] = f2b(ldmix(W1, (size_t)k * NHID + nn, isbf));
    }
    *(short8*)(w1f + (size_t)t * 8) = *(short8*)tmp;
}

__global__ void w2frag_kernel(const void* __restrict__ W2, ushort_t* __restrict__ w2f,
                              const int* __restrict__ flag) {
    int t = blockIdx.x * 256 + threadIdx.x;  // 1536 total
    if (t >= 8 * 3 * 64) return;
    int isbf = flag[0];
    int l = t % 64;
    int nt = (t / 64) % 3;
    int kb = t / 192;
    ushort_t tmp[8];
#pragma unroll
    for (int j = 0; j < 8; j++) {
        int k = kb * 32 + (l >> 4) * 8 + j;
        int nn = nt * 16 + (l & 15);
        tmp[j] = (nn < NCLASS) ? f2b(ldmix(W2, (size_t)k * NCLASS + nn, isbf)) : (ushort_t)0;
    }
    *(short8*)(w2f + (size_t)t * 8) = *(short8*)tmp;
}

// ---------------- fused MLP ----------------

template <int ISBF>
static __device__ __forceinline__ short8 load_afrag(const void* __restrict__ x, size_t base) {
    short8 av;
    if (ISBF) {
        av = *(const short8*)((const ushort_t*)x + base);
#pragma unroll
        for (int j = 0; j < 8; j++) {
            ushort_t u = (ushort_t)av[j];
            if ((u & 0x7F80u) == 0x7F80u) av[j] = 0;
        }
    } else {
        const float* xf = (const float*)x + base;
        f32x4 a0 = *(const f32x4*)xf;
        f32x4 a1 = *(const f32x4*)(xf + 4);
#pragma unroll
        for (int j = 0; j < 4; j++) {
            av[j] = (short)f2b(a0[j]);
            av[4 + j] = (short)f2b(a1[j]);
        }
    }
    return av;
}

#define APITCH 42

template <int ISBF>
static __device__ __forceinline__ void gemm1_staged(const void* __restrict__ x,
                                                    const ushort_t* __restrict__ w1f,
                                                    size_t xbase, ushort_t* Bl0, ushort_t* Bl1,
                                                    ushort_t* awr0, ushort_t* awr1,
                                                    const ushort_t* ard0, const ushort_t* ard1,
                                                    const ushort_t* brd0, const ushort_t* brd1,
                                                    f32x4 (&acc)[16], int wv, int l) {
    {
        short8 a0 = load_afrag<ISBF>(x, xbase);
        *(short8*)awr0 = a0;
        const ushort_t* src = w1f + (size_t)wv * 512 + (size_t)l * 8;
#pragma unroll
        for (int i = 0; i < 4; i++) gld_lds16(src + i * 2048, Bl0 + wv * 512 + i * 2048);
    }
    __syncthreads();

#pragma unroll
    for (int kb = 0; kb < 16; kb++) {
        const bool even = (kb & 1) == 0;
        const ushort_t* brd = even ? brd0 : brd1;
        const ushort_t* ard = even ? ard0 : ard1;
        ushort_t* awrn = even ? awr1 : awr0;
        ushort_t* bln = even ? Bl1 : Bl0;
        short8 an;
        if (kb < 15) {
            an = load_afrag<ISBF>(x, xbase + (size_t)(kb + 1) * 32);
            const ushort_t* src =
                w1f + (size_t)(kb + 1) * 8192 + (size_t)wv * 512 + (size_t)l * 8;
#pragma unroll
            for (int i = 0; i < 4; i++) gld_lds16(src + i * 2048, bln + wv * 512 + i * 2048);
        }
        short8 af = *(const short8*)ard;
#pragma unroll
        for (int nt = 0; nt < 16; nt++) {
            short8 bf = *(const short8*)(brd + nt * 512);
            acc[nt] = __builtin_amdgcn_mfma_f32_16x16x32_bf16(af, bf, acc[nt], 0, 0, 0);
        }
        if (kb < 15) *(short8*)awrn = an;
        __syncthreads();
    }
}

__global__ __launch_bounds__(256, 3) void mlp_kernel(const void* __restrict__ x,
                                                     const ushort_t* __restrict__ w1f,
                                                     const ushort_t* __restrict__ w2f,
                                                     const void* __restrict__ b1,
                                                     const void* __restrict__ b2,
                                                     void* __restrict__ h,
                                                     const int* __restrict__ flag, int zbf,
                                                     int n) {
    __shared__ __align__(16) ushort_t pool[21760];
    ushort_t* Bl0 = pool;
    ushort_t* Bl1 = pool + 8192;
    ushort_t* Al0 = pool + 16384;
    ushort_t* Al1 = pool + 16384 + 2688;
    ushort_t* Hl = pool;  // pitch 264

    const int t = threadIdx.x;
    const int isbf = flag[0];
    const int wv = t >> 6, l = t & 63;
    const int lq = l >> 4, lr = l & 15;
    const int m0 = blockIdx.x * 64;

    const int rS = t >> 2, qS = t & 3;
    int rowS = m0 + rS;
    if (rowS > n - 1) rowS = n - 1;
    const size_t xbase = (size_t)rowS * NFEAT + (size_t)qS * 8;
    ushort_t* awr0 = Al0 + rS * APITCH + qS * 8;
    ushort_t* awr1 = Al1 + rS * APITCH + qS * 8;
    const ushort_t* ard0 = Al0 + (wv * 16 + lr) * APITCH + lq * 8;
    const ushort_t* ard1 = Al1 + (wv * 16 + lr) * APITCH + lq * 8;
    const ushort_t* brd0 = Bl0 + l * 8;
    const ushort_t* brd1 = Bl1 + l * 8;

    f32x4 acc[16];
#pragma unroll
    for (int i = 0; i < 16; i++) acc[i] = (f32x4){0.f, 0.f, 0.f, 0.f};

    if (isbf)
        gemm1_staged<1>(x, w1f, xbase, Bl0, Bl1, awr0, awr1, ard0, ard1, brd0, brd1, acc, wv, l);
    else
        gemm1_staged<0>(x, w1f, xbase, Bl0, Bl1, awr0, awr1, ard0, ard1, brd0, brd1, acc, wv, l);

    float bias1 = ldmix(b1, 0, isbf);
#pragma unroll
    for (int nt = 0; nt < 16; nt++) {
#pragma unroll
        for (int i = 0; i < 4; i++) {
            float v = acc[nt][i] + bias1;
            v = fmaxf(v, 0.f);
            Hl[(wv * 16 + lq * 4 + i) * 264 + nt * 16 + lr] = f2b(v);
        }
    }
    __syncthreads();

    f32x4 acc2[3];
#pragma unroll
    for (int i = 0; i < 3; i++) acc2[i] = (f32x4){0.f, 0.f, 0.f, 0.f};
    const ushort_t* hp = Hl + (wv * 16 + lr) * 264 + lq * 8;
#pragma unroll
    for (int kb = 0; kb < 8; kb++) {
        short8 afrag = *(const short8*)(hp + kb * 32);
#pragma unroll
        for (int nt = 0; nt < 3; nt++) {
            short8 bfrag = *(const short8*)(w2f + ((size_t)(kb * 3 + nt) * 64 + l) * 8);
            acc2[nt] = __builtin_amdgcn_mfma_f32_16x16x32_bf16(afrag, bfrag, acc2[nt], 0, 0, 0);
        }
    }

    float bias2 = ldmix(b2, 0, isbf);
#pragma unroll
    for (int nt = 0; nt < 3; nt++) {
#pragma unroll
        for (int i = 0; i < 4; i++) {
            int rowg = m0 + wv * 16 + lq * 4 + i;
            int colg = nt * 16 + lr;
            if (rowg < n && colg < NCLASS)
                stz(h, (size_t)rowg * NCLASS + colg, zbf, acc2[nt][i] + bias2);
        }
    }
}

// ---------------- propagation: zout = 0.9 * A zin + 0.1 * h ----------------
// TWO nodes per wave, interleaved 8-deep gather batches: 16 independent
// gathers in flight per wave (two independent 8-chains; no long serial shfl
// prologue). lanes 0..39 = features. Idle-lane trick: lanes >= m hold
// c=0,v=0, so over-issued iterations contribute 0 and hit L1-hot row 0.

__global__ __launch_bounds__(256) void prop_kernel(const void* __restrict__ zin,
                                                   void* __restrict__ zout,
                                                   const void* __restrict__ h,
                                                   const int* __restrict__ row_start,
                                                   const int* __restrict__ deg,
                                                   const int2* __restrict__ cs, int n) {
    int g = blockIdx.x * 4 + (threadIdx.x >> 6);
    int lane = threadIdx.x & 63;
    int a = g * 2, b = g * 2 + 1;
    if (a >= n) return;
    const bool hasb = (b < n);
    int sa = row_start[a], da = deg[a];
    int sb = hasb ? row_start[b] : 0;
    int db = hasb ? deg[b] : 0;
    const bool laneok = lane < NCLASS;
    const ushort_t* zi = (const ushort_t*)zin;
    float acca = 0.f, accb = 0.f;
    int dmax = (da > db) ? da : db;
    for (int base = 0; base < dmax; base += 64) {
        int ma = da - base;
        ma = (ma < 0) ? 0 : ((ma > 64) ? 64 : ma);
        int mb = db - base;
        mb = (mb < 0) ? 0 : ((mb > 64) ? 64 : mb);
        int ca = 0, cb = 0;
        float va = 0.f, vb = 0.f;
        if (lane < ma) {
            int2 r = cs[(size_t)sa + base + lane];
            ca = r.x;
            __builtin_memcpy(&va, &r.y, 4);
        }
        if (lane < mb) {
            int2 r = cs[(size_t)sb + base + lane];
            cb = r.x;
            __builtin_memcpy(&vb, &r.y, 4);
        }
        int mm = (ma > mb) ? ma : mb;
        for (int j = 0; j < mm; j += 8) {
            int cca[8], ccb[8];
            float vva[8], vvb[8];
#pragma unroll
            for (int k = 0; k < 8; k++) {
                cca[k] = __shfl(ca, j + k);
                vva[k] = __shfl(va, j + k);
                ccb[k] = __shfl(cb, j + k);
                vvb[k] = __shfl(vb, j + k);
            }
            if (laneok) {
                float zva[8], zvb[8];
#pragma unroll
                for (int k = 0; k < 8; k++) zva[k] = b2f(zi[(size_t)cca[k] * NCLASS + lane]);
#pragma unroll
                for (int k = 0; k < 8; k++) zvb[k] = b2f(zi[(size_t)ccb[k] * NCLASS + lane]);
#pragma unroll
                for (int k = 0; k < 8; k++) acca += vva[k] * zva[k];
#pragma unroll
                for (int k = 0; k < 8; k++) accb += vvb[k] * zvb[k];
            }
        }
    }
    if (laneok) {
        {
            float hv = b2f(((const ushort_t*)h)[(size_t)a * NCLASS + lane]);
            ((ushort_t*)zout)[(size_t)a * NCLASS + lane] = f2b(0.9f * acca + 0.1f * hv);
        }
        if (hasb) {
            float hv = b2f(((const ushort_t*)h)[(size_t)b * NCLASS + lane]);
            ((ushort_t*)zout)[(size_t)b * NCLASS + lane] = f2b(0.9f * accb + 0.1f * hv);
        }
    }
}

// ---------------- log_softmax; out dtype follows detected input dtype ---------

__global__ __launch_bounds__(256) void lsm_kernel(const void* __restrict__ z,
                                                  void* __restrict__ out,
                                                  const int* __restrict__ flag, int n) {
    int w = blockIdx.x * 4 + (threadIdx.x >> 6);
    int lane = threadIdx.x & 63;
    if (w >= n) return;
    int isbf = flag[0];
    float v = (lane < NCLASS) ? b2f(((const ushort_t*)z)[(size_t)w * NCLASS + lane]) : -INFINITY;
    float m = v;
    for (int o = 32; o; o >>= 1) m = fmaxf(m, __shfl_xor(m, o));
    float e = (lane < NCLASS) ? __expf(v - m) : 0.f;
    float s = e;
    for (int o = 32; o; o >>= 1) s += __shfl_xor(s, o);
    if (lane < NCLASS) {
        float r = v - m - __logf(s);
        if (isbf) ((ushort_t*)out)[(size_t)w * NCLASS + lane] = f2b(r);
        else ((float*)out)[(size_t)w * NCLASS + lane] = r;
    }
}

// ---------------- launch ----------------

extern "C" void kernel_launch(void* const* d_in, const int* in_sizes, int n_in, void* d_out,
                              int out_size, void* d_ws, size_t ws_size, hipStream_t stream) {
    const void* x = d_in[0];
    const int* row = (const int*)d_in[1];
    const int* col = (const int*)d_in[2];
    const void* vals = d_in[3];
    const void* W1 = d_in[4];
    const void* b1 = d_in[5];
    const void* W2 = d_in[6];
    const void* b2 = d_in[7];

    const int N = in_sizes[0] / NFEAT;  // 100000
    const int E = in_sizes[1];          // 1600000

    const size_t ez = 2;  // z/h always bf16

    char* ws = (char*)d_ws;
    size_t off = 0;
    auto take = [&](size_t bytes) {
        size_t o = off;
        off = (off + bytes + 255) & ~(size_t)255;
        return (void*)(ws + o);
    };
    void* h = take((size_t)N * NCLASS * ez);
    void* zA = take((size_t)N * NCLASS * ez);
    void* zB = take((size_t)N * NCLASS * ez);
    int2* cs = (int2*)take((size_t)E * 8);
    int* deg = (int*)take((size_t)N * 4);
    int* row_start = (int*)take((size_t)N * 4);
    int* cursor = (int*)take((size_t)N * 4);
    ushort_t* w1f = (ushort_t*)take((size_t)NFEAT * NHID * 2);
    ushort_t* w2f = (ushort_t*)take((size_t)8 * 3 * 64 * 8 * 2);
    int* bsum = (int*)take(512 * 4);
    int* flag = (int*)take(256);

    const int NB = (N + 255) / 256;  // 391 <= 512
    const int EB = (E + 255) / 256;
    const int GB = (N + 63) / 64;
    const int PB = (N + 3) / 4;
    const int NSHARD = (N + 7) / 8;                 // 12500 nodes per XCD shard
    const int PB2 = ((N + 1) / 2 + 3) / 4;          // 2 nodes/wave, 4 waves/block

    detect_kernel<<<1, 256, 0, stream>>>((const ushort_t*)x, flag);

    // CSR build
    zero_kernel<<<(N + 255) / 256, 256, 0, stream>>>(deg, N);
    hist_kernel<<<EB, 256, 0, stream>>>(row, deg, E, N);
    scan_blocksum<<<NB, 256, 0, stream>>>(deg, bsum, N);
    scan_bsum_excl<<<1, 512, 0, stream>>>(bsum, NB);
    scan_emit<<<NB, 256, 0, stream>>>(deg, bsum, row_start, cursor, N);
    scatter_kernel<<<EB * 8, 256, 0, stream>>>(row, col, vals, cursor, cs, flag, E, N, NSHARD);

    // weight fragments
    w1frag_kernel<<<64, 256, 0, stream>>>(W1, w1f, flag);
    w2frag_kernel<<<6, 256, 0, stream>>>(W2, w2f, flag);

    // fused MLP -> h
    mlp_kernel<<<GB, 256, 0, stream>>>(x, w1f, w2f, b1, b2, h, flag, 1, N);

    // 10 propagation steps: h -> zA, then ping-pong zA/zB (ends in zB)
    prop_kernel<<<PB2, 256, 0, stream>>>(h, zA, h, row_start, deg, cs, N);
    {
        const void* zi = zA;
        void* zo = zB;
        for (int s = 1; s < 10; s++) {
            prop_kernel<<<PB2, 256, 0, stream>>>(zi, zo, h, row_start, deg, cs, N);
            const void* tmp = zi;
            zi = zo;
            zo = (void*)tmp;
        }
        lsm_kernel<<<PB, 256, 0, stream>>>(zi, d_out, flag, N);
    }
}

// Round 6
// 943.684 us; speedup vs baseline: 3.5922x; 1.0644x over previous
//
#include <hip/hip_runtime.h>

// APPNP: out = log_softmax(z_K), z_{k+1} = 0.9*A z_k + 0.1*h, z0 = h
// h = relu(x@W1+b1)@W2 + b2
// DTYPE-ADAPTIVE: float arrays may be fp32 or bf16; detected on-device from x's
// bit patterns (flag in ws). z/h always bf16. Edge records packed int2
// {col, fp32-bits(val)}.
// prop (r6 rewrite): 3-edges-per-gather-instruction. z rows are 40 bf16 =
// 20 dwords; lane-groups {0-19,20-39,40-59} each own an edge STREAM of the
// node (thirds of its edge list) and gather a different edge's z-row in the
// SAME instruction (20 lanes x 4B = 80B row). Per-wave in-flight edges
// triples (~8 load-insts x 3 edges) -- r4/r5 showed prop throughput scales
// with resident-waves x in-flight-per-wave, not bandwidth. Also kills the
// per-edge shfl broadcast storm (cs loaded per-group, 20-lane broadcast).
// scatter: XCD-sharded (block b&7 = shard) so each XCD's random 8B stores
// span 1.6MB < 4MB L2 and merge before eviction.

typedef unsigned short ushort_t;
typedef unsigned int uint_t;
typedef short short8 __attribute__((ext_vector_type(8)));
typedef float f32x4 __attribute__((ext_vector_type(4)));

#define NFEAT 512
#define NHID 256
#define NCLASS 40

static __device__ __forceinline__ float b2f(ushort_t u) {
    unsigned v = ((unsigned)u) << 16;
    float f;
    __builtin_memcpy(&f, &v, 4);
    return f;
}
static __device__ __forceinline__ ushort_t f2b(float f) {
    unsigned u;
    __builtin_memcpy(&u, &f, 4);
    unsigned r = u + 0x7FFFu + ((u >> 16) & 1u);
    return (ushort_t)(r >> 16);
}
static __device__ __forceinline__ ushort_t san_u(ushort_t u) {
    return ((u & 0x7F80u) == 0x7F80u) ? (ushort_t)0 : u;
}
static __device__ __forceinline__ float ldmix(const void* p, size_t i, int isbf) {
    if (isbf) return b2f(san_u(((const ushort_t*)p)[i]));
    return ((const float*)p)[i];
}
static __device__ __forceinline__ void stz(void* p, size_t i, int zbf, float v) {
    if (zbf) ((ushort_t*)p)[i] = f2b(v);
    else ((float*)p)[i] = v;
}

// async global->LDS, 16B per lane. LDS dest is wave-uniform base + lane*16.
static __device__ __forceinline__ void gld_lds16(const ushort_t* g, ushort_t* l) {
    __builtin_amdgcn_global_load_lds(
        (const __attribute__((address_space(1))) unsigned int*)g,
        (__attribute__((address_space(3))) unsigned int*)l, 16, 0, 0);
}

// ---------------- dtype detect ----------------
__global__ void detect_kernel(const ushort_t* __restrict__ x, int* __restrict__ flag) {
    __shared__ int cnt_s;
    if (threadIdx.x == 0) cnt_s = 0;
    __syncthreads();
    int c = 0;
    for (int i = threadIdx.x; i < 2048; i += 256) {
        ushort_t u = x[2 * i];
        int e = (u >> 7) & 0xFF;
        if (e >= 107 && e <= 141) c++;
    }
    atomicAdd(&cnt_s, c);
    __syncthreads();
    if (threadIdx.x == 0) flag[0] = (cnt_s >= 1024) ? 1 : 0;
}

// ---------------- CSR build ----------------

__global__ void zero_kernel(int* __restrict__ p, int n) {
    int i = blockIdx.x * 256 + threadIdx.x;
    if (i < n) p[i] = 0;
}

__global__ void hist_kernel(const int* __restrict__ row, int* __restrict__ deg, int e, int n) {
    int i = blockIdx.x * 256 + threadIdx.x;
    if (i < e) {
        int r = row[i];
        if ((unsigned)r < (unsigned)n) atomicAdd(&deg[r], 1);
    }
}

__global__ void scan_blocksum(const int* __restrict__ deg, int* __restrict__ bsum, int n) {
    __shared__ int s[256];
    int t = threadIdx.x;
    int i = blockIdx.x * 256 + t;
    s[t] = (i < n) ? deg[i] : 0;
    __syncthreads();
    for (int o = 128; o; o >>= 1) {
        if (t < o) s[t] += s[t + o];
        __syncthreads();
    }
    if (t == 0) bsum[blockIdx.x] = s[0];
}

__global__ void scan_bsum_excl(int* __restrict__ bsum, int nb) {
    __shared__ int s[512];
    int t = threadIdx.x;
    int v = (t < nb) ? bsum[t] : 0;
    int own = v;
    s[t] = v;
    __syncthreads();
    for (int o = 1; o < 512; o <<= 1) {
        int add = (t >= o) ? s[t - o] : 0;
        __syncthreads();
        s[t] += add;
        __syncthreads();
    }
    if (t < nb) bsum[t] = s[t] - own;
}

__global__ void scan_emit(const int* __restrict__ deg, const int* __restrict__ bsum,
                          int* __restrict__ row_start, int* __restrict__ cursor, int n) {
    __shared__ int s[256];
    int t = threadIdx.x;
    int i = blockIdx.x * 256 + t;
    int v = (i < n) ? deg[i] : 0;
    int own = v;
    s[t] = v;
    __syncthreads();
    for (int o = 1; o < 256; o <<= 1) {
        int add = (t >= o) ? s[t - o] : 0;
        __syncthreads();
        s[t] += add;
        __syncthreads();
    }
    if (i < n) {
        int rs = bsum[blockIdx.x] + s[t] - own;
        row_start[i] = rs;
        cursor[i] = rs;
    }
}

// XCD-sharded scatter: shard = blockIdx&7 (round-robin XCD dispatch), chunk =
// blockIdx>>3. Each block stores only rows in its shard's node range.
__global__ void scatter_kernel(const int* __restrict__ row, const int* __restrict__ col,
                               const void* __restrict__ vals, int* __restrict__ cursor,
                               int2* __restrict__ cs, const int* __restrict__ flag, int e,
                               int n, int nshard) {
    int shard = blockIdx.x & 7;
    int i = (blockIdx.x >> 3) * 256 + threadIdx.x;
    if (i >= e) return;
    int r = row[i];
    if ((unsigned)r >= (unsigned)n) return;
    int s0 = shard * nshard;
    if (r < s0 || r >= s0 + nshard) return;
    int isbf = flag[0];
    int p = atomicAdd(&cursor[r], 1);
    if ((unsigned)p < (unsigned)e) {
        int c = col[i];
        float v = ldmix(vals, i, isbf);
        int2 rec;
        rec.x = ((unsigned)c < (unsigned)n) ? c : 0;
        __builtin_memcpy(&rec.y, &v, 4);
        cs[p] = rec;
    }
}

// ---------------- weight fragment pre-layout (canonical bf16) ----------------
// B-frag (mfma_f32_16x16x32_bf16): lane l holds B[k=(l>>4)*8+j][n=l&15], j=0..7.
// w1f layout: [kb 0..15][nt 0..15][lane 0..63][8] -> per-kb slice is 16KB linear.

__global__ void w1frag_kernel(const void* __restrict__ W1, ushort_t* __restrict__ w1f,
                              const int* __restrict__ flag) {
    int t = blockIdx.x * 256 + threadIdx.x;  // 16384 total
    if (t >= 16 * 16 * 64) return;
    int isbf = flag[0];
    int l = t & 63, nt = (t >> 6) & 15, kb = t >> 10;
    ushort_t tmp[8];
#pragma unroll
    for (int j = 0; j < 8; j++) {
        int k = kb * 32 + (l >> 4) * 8 + j;
        int nn = nt * 16 + (l & 15);
        tmp[j] = f2b(ldmix(W1, (size_t)k * NHID + nn, isbf));
    }
    *(short8*)(w1f + (size_t)t * 8) = *(short8*)tmp;
}

__global__ void w2frag_kernel(const void* __restrict__ W2, ushort_t* __restrict__ w2f,
                              const int* __restrict__ flag) {
    int t = blockIdx.x * 256 + threadIdx.x;  // 1536 total
    if (t >= 8 * 3 * 64) return;
    int isbf = flag[0];
    int l = t % 64;
    int nt = (t / 64) % 3;
    int kb = t / 192;
    ushort_t tmp[8];
#pragma unroll
    for (int j = 0; j < 8; j++) {
        int k = kb * 32 + (l >> 4) * 8 + j;
        int nn = nt * 16 + (l & 15);
        tmp[j] = (nn < NCLASS) ? f2b(ldmix(W2, (size_t)k * NCLASS + nn, isbf)) : (ushort_t)0;
    }
    *(short8*)(w2f + (size_t)t * 8) = *(short8*)tmp;
}

// ---------------- fused MLP ----------------

template <int ISBF>
static __device__ __forceinline__ short8 load_afrag(const void* __restrict__ x, size_t base) {
    short8 av;
    if (ISBF) {
        av = *(const short8*)((const ushort_t*)x + base);
#pragma unroll
        for (int j = 0; j < 8; j++) {
            ushort_t u = (ushort_t)av[j];
            if ((u & 0x7F80u) == 0x7F80u) av[j] = 0;
        }
    } else {
        const float* xf = (const float*)x + base;
        f32x4 a0 = *(const f32x4*)xf;
        f32x4 a1 = *(const f32x4*)(xf + 4);
#pragma unroll
        for (int j = 0; j < 4; j++) {
            av[j] = (short)f2b(a0[j]);
            av[4 + j] = (short)f2b(a1[j]);
        }
    }
    return av;
}

#define APITCH 42

template <int ISBF>
static __device__ __forceinline__ void gemm1_staged(const void* __restrict__ x,
                                                    const ushort_t* __restrict__ w1f,
                                                    size_t xbase, ushort_t* Bl0, ushort_t* Bl1,
                                                    ushort_t* awr0, ushort_t* awr1,
                                                    const ushort_t* ard0, const ushort_t* ard1,
                                                    const ushort_t* brd0, const ushort_t* brd1,
                                                    f32x4 (&acc)[16], int wv, int l) {
    {
        short8 a0 = load_afrag<ISBF>(x, xbase);
        *(short8*)awr0 = a0;
        const ushort_t* src = w1f + (size_t)wv * 512 + (size_t)l * 8;
#pragma unroll
        for (int i = 0; i < 4; i++) gld_lds16(src + i * 2048, Bl0 + wv * 512 + i * 2048);
    }
    __syncthreads();

#pragma unroll
    for (int kb = 0; kb < 16; kb++) {
        const bool even = (kb & 1) == 0;
        const ushort_t* brd = even ? brd0 : brd1;
        const ushort_t* ard = even ? ard0 : ard1;
        ushort_t* awrn = even ? awr1 : awr0;
        ushort_t* bln = even ? Bl1 : Bl0;
        short8 an;
        if (kb < 15) {
            an = load_afrag<ISBF>(x, xbase + (size_t)(kb + 1) * 32);
            const ushort_t* src =
                w1f + (size_t)(kb + 1) * 8192 + (size_t)wv * 512 + (size_t)l * 8;
#pragma unroll
            for (int i = 0; i < 4; i++) gld_lds16(src + i * 2048, bln + wv * 512 + i * 2048);
        }
        short8 af = *(const short8*)ard;
#pragma unroll
        for (int nt = 0; nt < 16; nt++) {
            short8 bf = *(const short8*)(brd + nt * 512);
            acc[nt] = __builtin_amdgcn_mfma_f32_16x16x32_bf16(af, bf, acc[nt], 0, 0, 0);
        }
        if (kb < 15) *(short8*)awrn = an;
        __syncthreads();
    }
}

__global__ __launch_bounds__(256, 3) void mlp_kernel(const void* __restrict__ x,
                                                     const ushort_t* __restrict__ w1f,
                                                     const ushort_t* __restrict__ w2f,
                                                     const void* __restrict__ b1,
                                                     const void* __restrict__ b2,
                                                     void* __restrict__ h,
                                                     const int* __restrict__ flag, int zbf,
                                                     int n) {
    __shared__ __align__(16) ushort_t pool[21760];
    ushort_t* Bl0 = pool;
    ushort_t* Bl1 = pool + 8192;
    ushort_t* Al0 = pool + 16384;
    ushort_t* Al1 = pool + 16384 + 2688;
    ushort_t* Hl = pool;  // pitch 264

    const int t = threadIdx.x;
    const int isbf = flag[0];
    const int wv = t >> 6, l = t & 63;
    const int lq = l >> 4, lr = l & 15;
    const int m0 = blockIdx.x * 64;

    const int rS = t >> 2, qS = t & 3;
    int rowS = m0 + rS;
    if (rowS > n - 1) rowS = n - 1;
    const size_t xbase = (size_t)rowS * NFEAT + (size_t)qS * 8;
    ushort_t* awr0 = Al0 + rS * APITCH + qS * 8;
    ushort_t* awr1 = Al1 + rS * APITCH + qS * 8;
    const ushort_t* ard0 = Al0 + (wv * 16 + lr) * APITCH + lq * 8;
    const ushort_t* ard1 = Al1 + (wv * 16 + lr) * APITCH + lq * 8;
    const ushort_t* brd0 = Bl0 + l * 8;
    const ushort_t* brd1 = Bl1 + l * 8;

    f32x4 acc[16];
#pragma unroll
    for (int i = 0; i < 16; i++) acc[i] = (f32x4){0.f, 0.f, 0.f, 0.f};

    if (isbf)
        gemm1_staged<1>(x, w1f, xbase, Bl0, Bl1, awr0, awr1, ard0, ard1, brd0, brd1, acc, wv, l);
    else
        gemm1_staged<0>(x, w1f, xbase, Bl0, Bl1, awr0, awr1, ard0, ard1, brd0, brd1, acc, wv, l);

    float bias1 = ldmix(b1, 0, isbf);
#pragma unroll
    for (int nt = 0; nt < 16; nt++) {
#pragma unroll
        for (int i = 0; i < 4; i++) {
            float v = acc[nt][i] + bias1;
            v = fmaxf(v, 0.f);
            Hl[(wv * 16 + lq * 4 + i) * 264 + nt * 16 + lr] = f2b(v);
        }
    }
    __syncthreads();

    f32x4 acc2[3];
#pragma unroll
    for (int i = 0; i < 3; i++) acc2[i] = (f32x4){0.f, 0.f, 0.f, 0.f};
    const ushort_t* hp = Hl + (wv * 16 + lr) * 264 + lq * 8;
#pragma unroll
    for (int kb = 0; kb < 8; kb++) {
        short8 afrag = *(const short8*)(hp + kb * 32);
#pragma unroll
        for (int nt = 0; nt < 3; nt++) {
            short8 bfrag = *(const short8*)(w2f + ((size_t)(kb * 3 + nt) * 64 + l) * 8);
            acc2[nt] = __builtin_amdgcn_mfma_f32_16x16x32_bf16(afrag, bfrag, acc2[nt], 0, 0, 0);
        }
    }

    float bias2 = ldmix(b2, 0, isbf);
#pragma unroll
    for (int nt = 0; nt < 3; nt++) {
#pragma unroll
        for (int i = 0; i < 4; i++) {
            int rowg = m0 + wv * 16 + lq * 4 + i;
            int colg = nt * 16 + lr;
            if (rowg < n && colg < NCLASS)
                stz(h, (size_t)rowg * NCLASS + colg, zbf, acc2[nt][i] + bias2);
        }
    }
}

// ---------------- propagation: zout = 0.9 * A zin + 0.1 * h ----------------
// One node per wave. z row = 40 bf16 = 20 dwords. Lane-groups {0-19,20-39,
// 40-59} each own a third of the node's edge list; one dword-gather
// instruction fetches 3 different edges' z-rows (20 lanes x 4B = 80B each).
// Each lane accumulates 2 classes (packed bf16 pair) for its stream; the 3
// partial sums are combined with 2 shfl at the end. 8-deep batches -> ~24
// edges in flight per wave. Lanes 60-63 idle.

__global__ __launch_bounds__(256) void prop_kernel(const void* __restrict__ zin,
                                                   void* __restrict__ zout,
                                                   const void* __restrict__ h,
                                                   const int* __restrict__ row_start,
                                                   const int* __restrict__ deg,
                                                   const int2* __restrict__ cs, int n) {
    int w = blockIdx.x * 4 + (threadIdx.x >> 6);
    int lane = threadIdx.x & 63;
    if (w >= n) return;
    int start = row_start[w];
    int d = deg[w];
    const uint_t* zu = (const uint_t*)zin;

    int g = lane / 20;     // 0,1,2 active; 3 = idle lanes 60-63
    int cls2 = lane % 20;  // class-pair index
    int d3 = (d + 2) / 3;  // stream length (ceil)
    int st = g * d3;
    int len = d - st;
    if (len < 0) len = 0;
    if (len > d3) len = d3;
    if (g >= 3) len = 0;
    // safe base index for clamped/idle fetches
    int safebase = start;  // deg>=0; if d==0 loop doesn't run

    float acc0 = 0.f, acc1 = 0.f;
    for (int base = 0; base < d3; base += 8) {
        int2 rec[8];
#pragma unroll
        for (int q = 0; q < 8; q++) {
            int e = base + q;
            int ee = (e < len) ? e : ((len > 0) ? (len - 1) : 0);
            int idx = (len > 0) ? (start + st + ee) : safebase;
            rec[q] = cs[(size_t)idx];
        }
        uint_t zd[8];
        float vv[8];
#pragma unroll
        for (int q = 0; q < 8; q++) {
            float v;
            __builtin_memcpy(&v, &rec[q].y, 4);
            vv[q] = ((base + q) < len) ? v : 0.f;
            zd[q] = zu[(size_t)rec[q].x * 20 + cls2];
        }
#pragma unroll
        for (int q = 0; q < 8; q++) {
            uint_t ulo = zd[q] << 16;
            uint_t uhi = zd[q] & 0xFFFF0000u;
            float lo, hi;
            __builtin_memcpy(&lo, &ulo, 4);
            __builtin_memcpy(&hi, &uhi, 4);
            acc0 += vv[q] * lo;
            acc1 += vv[q] * hi;
        }
    }

    // combine the 3 stream partials into lanes 0-19
    float s0 = acc0 + __shfl(acc0, lane + 20) + __shfl(acc0, lane + 40);
    float s1 = acc1 + __shfl(acc1, lane + 20) + __shfl(acc1, lane + 40);

    if (lane < 20) {
        uint_t hu = ((const uint_t*)h)[(size_t)w * 20 + lane];
        uint_t hlo = hu << 16, hhi = hu & 0xFFFF0000u;
        float h0, h1;
        __builtin_memcpy(&h0, &hlo, 4);
        __builtin_memcpy(&h1, &hhi, 4);
        float r0 = 0.9f * s0 + 0.1f * h0;
        float r1 = 0.9f * s1 + 0.1f * h1;
        uint_t outw = (uint_t)f2b(r0) | ((uint_t)f2b(r1) << 16);
        ((uint_t*)zout)[(size_t)w * 20 + lane] = outw;
    }
}

// ---------------- log_softmax; out dtype follows detected input dtype ---------

__global__ __launch_bounds__(256) void lsm_kernel(const void* __restrict__ z,
                                                  void* __restrict__ out,
                                                  const int* __restrict__ flag, int n) {
    int w = blockIdx.x * 4 + (threadIdx.x >> 6);
    int lane = threadIdx.x & 63;
    if (w >= n) return;
    int isbf = flag[0];
    float v = (lane < NCLASS) ? b2f(((const ushort_t*)z)[(size_t)w * NCLASS + lane]) : -INFINITY;
    float m = v;
    for (int o = 32; o; o >>= 1) m = fmaxf(m, __shfl_xor(m, o));
    float e = (lane < NCLASS) ? __expf(v - m) : 0.f;
    float s = e;
    for (int o = 32; o; o >>= 1) s += __shfl_xor(s, o);
    if (lane < NCLASS) {
        float r = v - m - __logf(s);
        if (isbf) ((ushort_t*)out)[(size_t)w * NCLASS + lane] = f2b(r);
        else ((float*)out)[(size_t)w * NCLASS + lane] = r;
    }
}

// ---------------- launch ----------------

extern "C" void kernel_launch(void* const* d_in, const int* in_sizes, int n_in, void* d_out,
                              int out_size, void* d_ws, size_t ws_size, hipStream_t stream) {
    const void* x = d_in[0];
    const int* row = (const int*)d_in[1];
    const int* col = (const int*)d_in[2];
    const void* vals = d_in[3];
    const void* W1 = d_in[4];
    const void* b1 = d_in[5];
    const void* W2 = d_in[6];
    const void* b2 = d_in[7];

    const int N = in_sizes[0] / NFEAT;  // 100000
    const int E = in_sizes[1];          // 1600000

    const size_t ez = 2;  // z/h always bf16

    char* ws = (char*)d_ws;
    size_t off = 0;
    auto take = [&](size_t bytes) {
        size_t o = off;
        off = (off + bytes + 255) & ~(size_t)255;
        return (void*)(ws + o);
    };
    void* h = take((size_t)N * NCLASS * ez);
    void* zA = take((size_t)N * NCLASS * ez);
    void* zB = take((size_t)N * NCLASS * ez);
    int2* cs = (int2*)take((size_t)E * 8);
    int* deg = (int*)take((size_t)N * 4);
    int* row_start = (int*)take((size_t)N * 4);
    int* cursor = (int*)take((size_t)N * 4);
    ushort_t* w1f = (ushort_t*)take((size_t)NFEAT * NHID * 2);
    ushort_t* w2f = (ushort_t*)take((size_t)8 * 3 * 64 * 8 * 2);
    int* bsum = (int*)take(512 * 4);
    int* flag = (int*)take(256);

    const int NB = (N + 255) / 256;  // 391 <= 512
    const int EB = (E + 255) / 256;
    const int GB = (N + 63) / 64;
    const int PB = (N + 3) / 4;  // 1 node/wave, 4 waves/block
    const int NSHARD = (N + 7) / 8;

    detect_kernel<<<1, 256, 0, stream>>>((const ushort_t*)x, flag);

    // CSR build
    zero_kernel<<<(N + 255) / 256, 256, 0, stream>>>(deg, N);
    hist_kernel<<<EB, 256, 0, stream>>>(row, deg, E, N);
    scan_blocksum<<<NB, 256, 0, stream>>>(deg, bsum, N);
    scan_bsum_excl<<<1, 512, 0, stream>>>(bsum, NB);
    scan_emit<<<NB, 256, 0, stream>>>(deg, bsum, row_start, cursor, N);
    scatter_kernel<<<EB * 8, 256, 0, stream>>>(row, col, vals, cursor, cs, flag, E, N, NSHARD);

    // weight fragments
    w1frag_kernel<<<64, 256, 0, stream>>>(W1, w1f, flag);
    w2frag_kernel<<<6, 256, 0, stream>>>(W2, w2f, flag);

    // fused MLP -> h
    mlp_kernel<<<GB, 256, 0, stream>>>(x, w1f, w2f, b1, b2, h, flag, 1, N);

    // 10 propagation steps: h -> zA, then ping-pong zA/zB (ends in zB)
    prop_kernel<<<PB, 256, 0, stream>>>(h, zA, h, row_start, deg, cs, N);
    {
        const void* zi = zA;
        void* zo = zB;
        for (int s = 1; s < 10; s++) {
            prop_kernel<<<PB, 256, 0, stream>>>(zi, zo, h, row_start, deg, cs, N);
            const void* tmp = zi;
            zi = zo;
            zo = (void*)tmp;
        }
        lsm_kernel<<<PB, 256, 0, stream>>>(zi, d_out, flag, N);
    }
}